// Round 4
// baseline (10859.572 us; speedup 1.0000x reference)
//
#include <hip/hip_runtime.h>
#include <math.h>

#define N_NODES 50000
#define E_EDGES 800000
#define HDIM 256
#define NHEADS 8
#define HEADD 32
#define EDGED 3
#define NLAYERS 3

typedef unsigned int u32;

// ---------------------------------------------------------------------------
// edge_index layout detection: reference declares int64. If staged as raw
// int64, odd 32-bit words (high halves of values < 2^31) are ALL zero. If
// staged as int32, odd words are random node indices (P(all zero) ~ 0).
// flag[0] = 1 if int64 layout, 0 if int32.
// ---------------------------------------------------------------------------
__global__ __launch_bounds__(256) void detect_idx_k(const u32* __restrict__ w,
                                                    int* __restrict__ flag) {
  __shared__ u32 sm[256];
  u32 mx = 0;
  for (int k = threadIdx.x; k < 4096; k += 256) mx = max(mx, w[2 * k + 1]);
  sm[threadIdx.x] = mx;
  __syncthreads();
  for (int s = 128; s > 0; s >>= 1) {
    if (threadIdx.x < s)
      sm[threadIdx.x] = max(sm[threadIdx.x], sm[threadIdx.x + s]);
    __syncthreads();
  }
  if (threadIdx.x == 0) flag[0] = (sm[0] == 0) ? 1 : 0;
}

__global__ __launch_bounds__(256) void convert_idx_k(
    const u32* __restrict__ w, const int* __restrict__ flag,
    int* __restrict__ src32, int* __restrict__ dst32, int E_) {
  int e = blockIdx.x * blockDim.x + threadIdx.x;
  if (e >= E_) return;
  if (flag[0]) {  // int64: flat element j -> words 2j (lo), 2j+1 (hi)
    src32[e] = (int)w[2 * e];
    dst32[e] = (int)w[2 * (E_ + e)];
  } else {  // int32
    src32[e] = (int)w[e];
    dst32[e] = (int)w[E_ + e];
  }
}

// ---------------------------------------------------------------------------
// Input projection: h = relu(x @ W_in + b_in), x:(N,10), W:(10,256), fp32
// ---------------------------------------------------------------------------
__global__ __launch_bounds__(256) void input_proj_k(
    const float* __restrict__ x, const float* __restrict__ W,
    const float* __restrict__ b, float* __restrict__ h, int n) {
  __shared__ float ws[10 * 256];
  __shared__ float bs[256];
  int tid = threadIdx.x;
  for (int i = tid; i < 2560; i += 256) ws[i] = W[i];
  bs[tid] = b[tid];
  __syncthreads();
  int row0 = blockIdx.x * 32;
  for (int rr = 0; rr < 32; ++rr) {
    int row = row0 + rr;
    if (row >= n) break;
    float acc = bs[tid];
#pragma unroll
    for (int i = 0; i < 10; ++i) acc += x[row * 10 + i] * ws[i * 256 + tid];
    h[(size_t)row * 256 + tid] = fmaxf(acc, 0.f);
  }
}

// ---------------------------------------------------------------------------
// Tiled fp32 GEMM: C = act(A @ B + bias)
// A1:(M,K1) row-major; if CONCAT, logical A = [A1 | A2] (Ktot = 2*K1).
// B:(Ktot,Ncol) row-major. 64x64 tile, 256 thr, 4x4 acc/thread, K-tile 16.
// ---------------------------------------------------------------------------
template <bool CONCAT, bool RELU>
__global__ __launch_bounds__(256) void gemm_k(
    const float* __restrict__ A1, const float* __restrict__ A2,
    const float* __restrict__ B, const float* __restrict__ bias,
    float* __restrict__ C, int M, int K1, int Ktot, int Ncol) {
  __shared__ float As[16][64];
  __shared__ float Bs[16][64];
  int tid = threadIdx.x;
  int tx = tid & 15, ty = tid >> 4;
  int row0 = blockIdx.y * 64, col0 = blockIdx.x * 64;
  float acc[4][4] = {};
  int arow = tid >> 2;        // 0..63
  int akc = (tid & 3) * 4;    // 0,4,8,12
  int brow = tid >> 4;        // 0..15
  int bcol = (tid & 15) * 4;  // 0..60

  for (int k0 = 0; k0 < Ktot; k0 += 16) {
    const float* Ap = A1;
    int kk = k0;
    if (CONCAT && k0 >= K1) { Ap = A2; kk = k0 - K1; }
    int r = row0 + arow;
    float4 av = make_float4(0.f, 0.f, 0.f, 0.f);
    if (r < M) av = *(const float4*)(Ap + (size_t)r * K1 + kk + akc);
    As[akc + 0][arow] = av.x;
    As[akc + 1][arow] = av.y;
    As[akc + 2][arow] = av.z;
    As[akc + 3][arow] = av.w;
    float4 bv = *(const float4*)(B + (size_t)(k0 + brow) * Ncol + col0 + bcol);
    *(float4*)&Bs[brow][bcol] = bv;
    __syncthreads();
#pragma unroll
    for (int k = 0; k < 16; ++k) {
      float a[4], bb[4];
#pragma unroll
      for (int i = 0; i < 4; ++i) a[i] = As[k][ty * 4 + i];
#pragma unroll
      for (int j = 0; j < 4; ++j) bb[j] = Bs[k][tx * 4 + j];
#pragma unroll
      for (int i = 0; i < 4; ++i)
#pragma unroll
        for (int j = 0; j < 4; ++j) acc[i][j] += a[i] * bb[j];
    }
    __syncthreads();
  }

#pragma unroll
  for (int i = 0; i < 4; ++i) {
    int r = row0 + ty * 4 + i;
    if (r >= M) continue;
    int c = col0 + tx * 4;
    float4 ov;
    float* po = &ov.x;
#pragma unroll
    for (int j = 0; j < 4; ++j) {
      float v = acc[i][j];
      if (bias) v += bias[c + j];
      if (RELU) v = fmaxf(v, 0.f);
      po[j] = v;
    }
    *(float4*)(C + (size_t)r * Ncol + c) = ov;
  }
}

// ---------------------------------------------------------------------------
// Edge attention logits: one wave per edge.
// attn[e,h] = leakyrelu(scale*dot(Q[dst,h,:],K[src,h,:]) + ea[e,:]@We[:,h])
// ---------------------------------------------------------------------------
__global__ __launch_bounds__(256) void edge_attn_k(
    const float* __restrict__ Q, const float* __restrict__ K,
    const float* __restrict__ ea, const float* __restrict__ We_l,
    const int* __restrict__ src, const int* __restrict__ dst,
    float* __restrict__ attn, int E_) {
  int e = (blockIdx.x * blockDim.x + threadIdx.x) >> 6;
  if (e >= E_) return;
  int lane = threadIdx.x & 63;
  int s = src[e], d = dst[e];
  float4 q4 = ((const float4*)(Q + (size_t)d * 256))[lane];
  float4 k4 = ((const float4*)(K + (size_t)s * 256))[lane];
  float p = q4.x * k4.x + q4.y * k4.y + q4.z * k4.z + q4.w * k4.w;
  p += __shfl_xor(p, 1);
  p += __shfl_xor(p, 2);
  p += __shfl_xor(p, 4);
  if ((lane & 7) == 0) {
    int hh = lane >> 3;
    float bias = ea[(size_t)e * 3 + 0] * We_l[0 * 8 + hh] +
                 ea[(size_t)e * 3 + 1] * We_l[1 * 8 + hh] +
                 ea[(size_t)e * 3 + 2] * We_l[2 * 8 + hh];
    float a = p * 0.17677669529663687f + bias;  // 1/sqrt(32)
    a = (a > 0.f) ? a : 0.2f * a;               // leaky_relu 0.2
    attn[(size_t)e * 8 + hh] = a;
  }
}

// ---------------------------------------------------------------------------
// Global max, two-stage deterministic
// ---------------------------------------------------------------------------
__global__ __launch_bounds__(256) void rmax1_k(const float* __restrict__ a,
                                               int n, float* __restrict__ part) {
  float m = -INFINITY;
  for (int i = blockIdx.x * blockDim.x + threadIdx.x; i < n;
       i += gridDim.x * blockDim.x)
    m = fmaxf(m, a[i]);
  for (int d = 1; d < 64; d <<= 1) m = fmaxf(m, __shfl_xor(m, d));
  __shared__ float sm[4];
  if ((threadIdx.x & 63) == 0) sm[threadIdx.x >> 6] = m;
  __syncthreads();
  if (threadIdx.x == 0)
    part[blockIdx.x] = fmaxf(fmaxf(sm[0], sm[1]), fmaxf(sm[2], sm[3]));
}

__global__ __launch_bounds__(256) void rmax2_k(const float* __restrict__ part,
                                               int nb, float* __restrict__ gmax) {
  float m = -INFINITY;
  for (int i = threadIdx.x; i < nb; i += 256) m = fmaxf(m, part[i]);
  for (int d = 1; d < 64; d <<= 1) m = fmaxf(m, __shfl_xor(m, d));
  __shared__ float sm[4];
  if ((threadIdx.x & 63) == 0) sm[threadIdx.x >> 6] = m;
  __syncthreads();
  if (threadIdx.x == 0)
    gmax[0] = fmaxf(fmaxf(sm[0], sm[1]), fmaxf(sm[2], sm[3]));
}

// ---------------------------------------------------------------------------
// attn_exp = exp(attn - gmax) in-place; atomic segment-sum by dst
// ---------------------------------------------------------------------------
__global__ __launch_bounds__(256) void attn_exp_sum_k(
    float* __restrict__ attn, const int* __restrict__ dst,
    const float* __restrict__ gmax, float* __restrict__ asum, int total) {
  int t = blockIdx.x * blockDim.x + threadIdx.x;
  if (t >= total) return;
  float M = gmax[0];
  int e = t >> 3, hh = t & 7;
  float v = expf(attn[t] - M);
  attn[t] = v;
  atomicAdd(asum + (size_t)dst[e] * 8 + hh, v);
}

// ---------------------------------------------------------------------------
// agg[dst] += V[src] * attn_exp/clip(sum) — one wave per edge
// ---------------------------------------------------------------------------
__global__ __launch_bounds__(256) void aggregate_k(
    const float* __restrict__ V, const float* __restrict__ attn,
    const float* __restrict__ asum, const int* __restrict__ src,
    const int* __restrict__ dst, float* __restrict__ agg, int E_) {
  int e = (blockIdx.x * blockDim.x + threadIdx.x) >> 6;
  if (e >= E_) return;
  int lane = threadIdx.x & 63;
  int s = src[e], d = dst[e];
  int hh = lane >> 3;
  float w = attn[(size_t)e * 8 + hh] /
            fmaxf(asum[(size_t)d * 8 + hh], 1e-12f);
  float4 v4 = ((const float4*)(V + (size_t)s * 256))[lane];
  float* p = agg + (size_t)d * 256 + lane * 4;
  atomicAdd(p + 0, v4.x * w);
  atomicAdd(p + 1, v4.y * w);
  atomicAdd(p + 2, v4.z * w);
  atomicAdd(p + 3, v4.w * w);
}

// ---------------------------------------------------------------------------
// h = LayerNorm(h + upd) * gamma + beta (in-place on h); one wave per row
// ---------------------------------------------------------------------------
__global__ __launch_bounds__(256) void add_ln_k(
    float* __restrict__ h, const float* __restrict__ upd,
    const float* __restrict__ g, const float* __restrict__ b, int n) {
  int row = (blockIdx.x * blockDim.x + threadIdx.x) >> 6;
  if (row >= n) return;
  int lane = threadIdx.x & 63;
  float4 hv = ((const float4*)(h + (size_t)row * 256))[lane];
  float4 uv = ((const float4*)(upd + (size_t)row * 256))[lane];
  float4 s = make_float4(hv.x + uv.x, hv.y + uv.y, hv.z + uv.z, hv.w + uv.w);
  float sum = s.x + s.y + s.z + s.w;
  float sq = s.x * s.x + s.y * s.y + s.z * s.z + s.w * s.w;
  for (int d = 1; d < 64; d <<= 1) {
    sum += __shfl_xor(sum, d);
    sq += __shfl_xor(sq, d);
  }
  float mean = sum * (1.f / 256.f);
  float var = sq * (1.f / 256.f) - mean * mean;
  float r = rsqrtf(var + 1e-5f);
  float4 g4 = ((const float4*)g)[lane];
  float4 b4 = ((const float4*)b)[lane];
  float4 o;
  o.x = (s.x - mean) * r * g4.x + b4.x;
  o.y = (s.y - mean) * r * g4.y + b4.y;
  o.z = (s.z - mean) * r * g4.z + b4.z;
  o.w = (s.w - mean) * r * g4.w + b4.w;
  ((float4*)(h + (size_t)row * 256))[lane] = o;
}

// ---------------------------------------------------------------------------
// out[n] = t[n,:128] @ W_h2 + b_h2 — one wave per row; fp32 out
// ---------------------------------------------------------------------------
__global__ __launch_bounds__(256) void head2_k(
    const float* __restrict__ t, const float* __restrict__ W2,
    const float* __restrict__ b2, float* __restrict__ out, int n) {
  int row = (blockIdx.x * blockDim.x + threadIdx.x) >> 6;
  if (row >= n) return;
  int lane = threadIdx.x & 63;
  float acc = t[(size_t)row * 128 + lane] * W2[lane] +
              t[(size_t)row * 128 + 64 + lane] * W2[64 + lane];
  for (int d = 1; d < 64; d <<= 1) acc += __shfl_xor(acc, d);
  if (lane == 0) out[row] = acc + b2[0];
}

// ---------------------------------------------------------------------------
extern "C" void kernel_launch(void* const* d_in, const int* in_sizes, int n_in,
                              void* d_out, int out_size, void* d_ws,
                              size_t ws_size, hipStream_t stream) {
  const float* x = (const float*)d_in[0];
  const float* edge_attr = (const float*)d_in[1];
  const float* W_in = (const float*)d_in[2];
  const float* b_in = (const float*)d_in[3];
  const float* Wq = (const float*)d_in[4];
  const float* Wk = (const float*)d_in[5];
  const float* Wv = (const float*)d_in[6];
  const float* We = (const float*)d_in[7];
  const float* Wo = (const float*)d_in[8];
  const float* bo = (const float*)d_in[9];
  const float* Wm = (const float*)d_in[10];
  const float* bm = (const float*)d_in[11];
  const float* gamma = (const float*)d_in[12];
  const float* beta = (const float*)d_in[13];
  const float* W_h1 = (const float*)d_in[14];
  const float* b_h1 = (const float*)d_in[15];
  const float* W_h2 = (const float*)d_in[16];
  const float* b_h2 = (const float*)d_in[17];
  const u32* eidx_w = (const u32*)d_in[18];

  // ws layout (fp32 elems): 4*51.2MB + 25.6 + 1.6 + 6.4 = 238 MB total.
  // (Round-1's 283MB layout faulted -> keep under ~256MB.)
  float* ws = (float*)d_ws;
  const size_t NH_ = (size_t)N_NODES * HDIM;
  float* h = ws;                                  // N*256, persists
  float* Qb = h + NH_;                            // N*256 (Q -> agg)
  float* Kb = Qb + NH_;                           // N*256 (K -> Wo-out)
  float* Vb = Kb + NH_;                           // N*256 (V -> upd)
  float* attn = Vb + NH_;                         // E*8
  float* asum = attn + (size_t)E_EDGES * NHEADS;  // N*8
  float* part = asum + (size_t)N_NODES * NHEADS;  // 1024
  float* gmax = part + 1024;                      // 1
  int* idxflag = (int*)(gmax + 1);                // 1
  int* srcI = idxflag + 1;                        // E
  int* dstI = srcI + E_EDGES;                     // E

  detect_idx_k<<<1, 256, 0, stream>>>(eidx_w, idxflag);
  convert_idx_k<<<(E_EDGES + 255) / 256, 256, 0, stream>>>(
      eidx_w, idxflag, srcI, dstI, E_EDGES);

  input_proj_k<<<(N_NODES + 31) / 32, 256, 0, stream>>>(x, W_in, b_in, h,
                                                        N_NODES);
  dim3 g256(HDIM / 64, (N_NODES + 63) / 64);
  const int ewaves_grid = (E_EDGES * 64) / 256;  // wave-per-edge kernels
  const int rowwave_grid = (N_NODES * 64 + 255) / 256;

  for (int l = 0; l < NLAYERS; ++l) {
    const float* Wq_l = Wq + (size_t)l * HDIM * HDIM;
    const float* Wk_l = Wk + (size_t)l * HDIM * HDIM;
    const float* Wv_l = Wv + (size_t)l * HDIM * HDIM;
    const float* We_l = We + (size_t)l * EDGED * NHEADS;
    const float* Wo_l = Wo + (size_t)l * HDIM * HDIM;
    const float* bo_l = bo + (size_t)l * HDIM;
    const float* Wm_l = Wm + (size_t)l * 2 * HDIM * HDIM;
    const float* bm_l = bm + (size_t)l * HDIM;

    gemm_k<false, false><<<g256, 256, 0, stream>>>(
        h, nullptr, Wq_l, nullptr, Qb, N_NODES, HDIM, HDIM, HDIM);
    gemm_k<false, false><<<g256, 256, 0, stream>>>(
        h, nullptr, Wk_l, nullptr, Kb, N_NODES, HDIM, HDIM, HDIM);
    gemm_k<false, false><<<g256, 256, 0, stream>>>(
        h, nullptr, Wv_l, nullptr, Vb, N_NODES, HDIM, HDIM, HDIM);
    edge_attn_k<<<ewaves_grid, 256, 0, stream>>>(Qb, Kb, edge_attr, We_l, srcI,
                                                 dstI, attn, E_EDGES);
    rmax1_k<<<1024, 256, 0, stream>>>(attn, E_EDGES * NHEADS, part);
    rmax2_k<<<1, 256, 0, stream>>>(part, 1024, gmax);
    hipMemsetAsync(asum, 0, (size_t)N_NODES * NHEADS * sizeof(float), stream);
    attn_exp_sum_k<<<(E_EDGES * NHEADS + 255) / 256, 256, 0, stream>>>(
        attn, dstI, gmax, asum, E_EDGES * NHEADS);
    // agg reuses Qb (Q dead after edge_attn)
    hipMemsetAsync(Qb, 0, NH_ * sizeof(float), stream);
    aggregate_k<<<ewaves_grid, 256, 0, stream>>>(Vb, attn, asum, srcI, dstI,
                                                 Qb, E_EDGES);
    // tmp = agg @ Wo + bo -> Kb (K dead)
    gemm_k<false, false><<<g256, 256, 0, stream>>>(
        Qb, nullptr, Wo_l, bo_l, Kb, N_NODES, HDIM, HDIM, HDIM);
    // upd = relu([h | tmp] @ Wm + bm) -> Vb (V dead after aggregate)
    gemm_k<true, true><<<g256, 256, 0, stream>>>(
        h, Kb, Wm_l, bm_l, Vb, N_NODES, HDIM, 2 * HDIM, HDIM);
    add_ln_k<<<rowwave_grid, 256, 0, stream>>>(h, Vb, gamma + (size_t)l * HDIM,
                                               beta + (size_t)l * HDIM,
                                               N_NODES);
  }
  // head: t = relu(h @ W_h1 + b_h1) -> Qb (N*128); out = t @ W_h2 + b_h2
  dim3 gh(128 / 64, (N_NODES + 63) / 64);
  gemm_k<false, true><<<gh, 256, 0, stream>>>(h, nullptr, W_h1, b_h1, Qb,
                                              N_NODES, HDIM, HDIM, 128);
  head2_k<<<rowwave_grid, 256, 0, stream>>>(Qb, W_h2, b_h2, (float*)d_out,
                                            N_NODES);
}

// Round 5
// 3263.025 us; speedup vs baseline: 3.3281x; 3.3281x over previous
//
#include <hip/hip_runtime.h>
#include <math.h>

#define N_NODES 50000
#define E_EDGES 800000
#define HDIM 256
#define NHEADS 8
#define HEADD 32
#define EDGED 3
#define NLAYERS 3

typedef unsigned int u32;

// ---------------------------------------------------------------------------
// edge_index layout detection (int64 vs int32 staging), as in round 4.
// ---------------------------------------------------------------------------
__global__ __launch_bounds__(256) void detect_idx_k(const u32* __restrict__ w,
                                                    int* __restrict__ flag) {
  __shared__ u32 sm[256];
  u32 mx = 0;
  for (int k = threadIdx.x; k < 4096; k += 256) mx = max(mx, w[2 * k + 1]);
  sm[threadIdx.x] = mx;
  __syncthreads();
  for (int s = 128; s > 0; s >>= 1) {
    if (threadIdx.x < s)
      sm[threadIdx.x] = max(sm[threadIdx.x], sm[threadIdx.x + s]);
    __syncthreads();
  }
  if (threadIdx.x == 0) flag[0] = (sm[0] == 0) ? 1 : 0;
}

__global__ __launch_bounds__(256) void convert_idx_k(
    const u32* __restrict__ w, const int* __restrict__ flag,
    int* __restrict__ src32, int* __restrict__ dst32, int E_) {
  int e = blockIdx.x * blockDim.x + threadIdx.x;
  if (e >= E_) return;
  if (flag[0]) {
    src32[e] = (int)w[2 * e];
    dst32[e] = (int)w[2 * (E_ + e)];
  } else {
    src32[e] = (int)w[e];
    dst32[e] = (int)w[E_ + e];
  }
}

// ---------------------------------------------------------------------------
// CSR build: histogram by dst, exclusive scan, scatter (src + orig edge id)
// ---------------------------------------------------------------------------
__global__ __launch_bounds__(256) void hist_k(const int* __restrict__ dst,
                                              int* __restrict__ dcnt, int E_) {
  int e = blockIdx.x * blockDim.x + threadIdx.x;
  if (e >= E_) return;
  atomicAdd(&dcnt[dst[e]], 1);
}

// single-block exclusive scan: rowptr[0]=0, rowptr[i+1]=sum(deg[0..i])
__global__ __launch_bounds__(256) void scan_k(const int* __restrict__ deg,
                                              int* __restrict__ rowptr, int n) {
  __shared__ int tmp[256];
  __shared__ int carry;
  if (threadIdx.x == 0) { carry = 0; rowptr[0] = 0; }
  __syncthreads();
  for (int base = 0; base < n; base += 256) {
    int i = base + threadIdx.x;
    int v = (i < n) ? deg[i] : 0;
    tmp[threadIdx.x] = v;
    __syncthreads();
    for (int off = 1; off < 256; off <<= 1) {
      int t = (threadIdx.x >= off) ? tmp[threadIdx.x - off] : 0;
      __syncthreads();
      tmp[threadIdx.x] += t;
      __syncthreads();
    }
    if (i < n) rowptr[i + 1] = carry + tmp[threadIdx.x];
    __syncthreads();
    if (threadIdx.x == 0) carry += tmp[255];
    __syncthreads();
  }
}

__global__ __launch_bounds__(256) void fill_k(
    const int* __restrict__ srcI, const int* __restrict__ dstI,
    const int* __restrict__ rowptr, int* __restrict__ cursor,
    int* __restrict__ src_sorted, int* __restrict__ eorig, int E_) {
  int e = blockIdx.x * blockDim.x + threadIdx.x;
  if (e >= E_) return;
  int d = dstI[e];
  int p = rowptr[d] + atomicAdd(&cursor[d], 1);
  src_sorted[p] = srcI[e];
  eorig[p] = e;
}

// ---------------------------------------------------------------------------
// Input projection: h = relu(x @ W_in + b_in)
// ---------------------------------------------------------------------------
__global__ __launch_bounds__(256) void input_proj_k(
    const float* __restrict__ x, const float* __restrict__ W,
    const float* __restrict__ b, float* __restrict__ h, int n) {
  __shared__ float ws[10 * 256];
  __shared__ float bs[256];
  int tid = threadIdx.x;
  for (int i = tid; i < 2560; i += 256) ws[i] = W[i];
  bs[tid] = b[tid];
  __syncthreads();
  int row0 = blockIdx.x * 32;
  for (int rr = 0; rr < 32; ++rr) {
    int row = row0 + rr;
    if (row >= n) break;
    float acc = bs[tid];
#pragma unroll
    for (int i = 0; i < 10; ++i) acc += x[row * 10 + i] * ws[i * 256 + tid];
    h[(size_t)row * 256 + tid] = fmaxf(acc, 0.f);
  }
}

// ---------------------------------------------------------------------------
// Tiled fp32 GEMM (as round 4): C = act(A @ B + bias)
// ---------------------------------------------------------------------------
template <bool CONCAT, bool RELU>
__global__ __launch_bounds__(256) void gemm_k(
    const float* __restrict__ A1, const float* __restrict__ A2,
    const float* __restrict__ B, const float* __restrict__ bias,
    float* __restrict__ C, int M, int K1, int Ktot, int Ncol) {
  __shared__ float As[16][64];
  __shared__ float Bs[16][64];
  int tid = threadIdx.x;
  int tx = tid & 15, ty = tid >> 4;
  int row0 = blockIdx.y * 64, col0 = blockIdx.x * 64;
  float acc[4][4] = {};
  int arow = tid >> 2;
  int akc = (tid & 3) * 4;
  int brow = tid >> 4;
  int bcol = (tid & 15) * 4;

  for (int k0 = 0; k0 < Ktot; k0 += 16) {
    const float* Ap = A1;
    int kk = k0;
    if (CONCAT && k0 >= K1) { Ap = A2; kk = k0 - K1; }
    int r = row0 + arow;
    float4 av = make_float4(0.f, 0.f, 0.f, 0.f);
    if (r < M) av = *(const float4*)(Ap + (size_t)r * K1 + kk + akc);
    As[akc + 0][arow] = av.x;
    As[akc + 1][arow] = av.y;
    As[akc + 2][arow] = av.z;
    As[akc + 3][arow] = av.w;
    float4 bv = *(const float4*)(B + (size_t)(k0 + brow) * Ncol + col0 + bcol);
    *(float4*)&Bs[brow][bcol] = bv;
    __syncthreads();
#pragma unroll
    for (int k = 0; k < 16; ++k) {
      float a[4], bb[4];
#pragma unroll
      for (int i = 0; i < 4; ++i) a[i] = As[k][ty * 4 + i];
#pragma unroll
      for (int j = 0; j < 4; ++j) bb[j] = Bs[k][tx * 4 + j];
#pragma unroll
      for (int i = 0; i < 4; ++i)
#pragma unroll
        for (int j = 0; j < 4; ++j) acc[i][j] += a[i] * bb[j];
    }
    __syncthreads();
  }

#pragma unroll
  for (int i = 0; i < 4; ++i) {
    int r = row0 + ty * 4 + i;
    if (r >= M) continue;
    int c = col0 + tx * 4;
    float4 ov;
    float* po = &ov.x;
#pragma unroll
    for (int j = 0; j < 4; ++j) {
      float v = acc[i][j];
      if (bias) v += bias[c + j];
      if (RELU) v = fmaxf(v, 0.f);
      po[j] = v;
    }
    *(float4*)(C + (size_t)r * Ncol + c) = ov;
  }
}

// ---------------------------------------------------------------------------
// Per-node attention logits over CSR segment: one wave per node.
// Q row kept in registers; K rows gathered per incoming edge.
// attn[p,h] = leakyrelu(scale*dot(Q[node,h],K[src,h]) + edge_attr[eorig]@We)
// ---------------------------------------------------------------------------
__global__ __launch_bounds__(256) void node_attn_k(
    const float* __restrict__ Q, const float* __restrict__ K,
    const float* __restrict__ ea, const float* __restrict__ We_l,
    const int* __restrict__ rowptr, const int* __restrict__ src_sorted,
    const int* __restrict__ eorig, float* __restrict__ attn, int n) {
  int node = (blockIdx.x * blockDim.x + threadIdx.x) >> 6;
  if (node >= n) return;
  int lane = threadIdx.x & 63;
  float4 q4 = ((const float4*)(Q + (size_t)node * 256))[lane];
  int start = rowptr[node], end = rowptr[node + 1];
  int hh = lane >> 3;
  float w0 = We_l[0 * 8 + hh], w1 = We_l[1 * 8 + hh], w2 = We_l[2 * 8 + hh];
  for (int p = start; p < end; ++p) {
    int s = src_sorted[p];
    float4 k4 = ((const float4*)(K + (size_t)s * 256))[lane];
    float d = q4.x * k4.x + q4.y * k4.y + q4.z * k4.z + q4.w * k4.w;
    d += __shfl_xor(d, 1);
    d += __shfl_xor(d, 2);
    d += __shfl_xor(d, 4);
    if ((lane & 7) == 0) {
      int e = eorig[p];
      float bias = ea[(size_t)e * 3 + 0] * w0 + ea[(size_t)e * 3 + 1] * w1 +
                   ea[(size_t)e * 3 + 2] * w2;
      float a = d * 0.17677669529663687f + bias;  // 1/sqrt(32)
      a = (a > 0.f) ? a : 0.2f * a;               // leaky_relu 0.2
      attn[(size_t)p * 8 + hh] = a;
    }
  }
}

// ---------------------------------------------------------------------------
// Global max, two-stage deterministic
// ---------------------------------------------------------------------------
__global__ __launch_bounds__(256) void rmax1_k(const float* __restrict__ a,
                                               int n, float* __restrict__ part) {
  float m = -INFINITY;
  for (int i = blockIdx.x * blockDim.x + threadIdx.x; i < n;
       i += gridDim.x * blockDim.x)
    m = fmaxf(m, a[i]);
  for (int d = 1; d < 64; d <<= 1) m = fmaxf(m, __shfl_xor(m, d));
  __shared__ float sm[4];
  if ((threadIdx.x & 63) == 0) sm[threadIdx.x >> 6] = m;
  __syncthreads();
  if (threadIdx.x == 0)
    part[blockIdx.x] = fmaxf(fmaxf(sm[0], sm[1]), fmaxf(sm[2], sm[3]));
}

__global__ __launch_bounds__(256) void rmax2_k(const float* __restrict__ part,
                                               int nb, float* __restrict__ gmax) {
  float m = -INFINITY;
  for (int i = threadIdx.x; i < nb; i += 256) m = fmaxf(m, part[i]);
  for (int d = 1; d < 64; d <<= 1) m = fmaxf(m, __shfl_xor(m, d));
  __shared__ float sm[4];
  if ((threadIdx.x & 63) == 0) sm[threadIdx.x >> 6] = m;
  __syncthreads();
  if (threadIdx.x == 0)
    gmax[0] = fmaxf(fmaxf(sm[0], sm[1]), fmaxf(sm[2], sm[3]));
}

// ---------------------------------------------------------------------------
// Per-node softmax + weighted-V aggregation: one wave per node, no atomics.
// Pass 1: per-head sum of exp over segment (8 groups x 8 heads per wave).
// Pass 2: acc += exp(attn-M)/sum * V[src]; single 1KB store per node.
// ---------------------------------------------------------------------------
__global__ __launch_bounds__(256) void node_agg_k(
    const float* __restrict__ V, const float* __restrict__ attn,
    const float* __restrict__ gmax, const int* __restrict__ rowptr,
    const int* __restrict__ src_sorted, float* __restrict__ agg, int n) {
  int node = (blockIdx.x * blockDim.x + threadIdx.x) >> 6;
  if (node >= n) return;
  int lane = threadIdx.x & 63;
  int start = rowptr[node], end = rowptr[node + 1];
  float M = gmax[0];
  int g = lane >> 3, hh = lane & 7;
  float sl = 0.f;
  for (int p = start + g; p < end; p += 8)
    sl += expf(attn[(size_t)p * 8 + hh] - M);
  sl += __shfl_xor(sl, 8);
  sl += __shfl_xor(sl, 16);
  sl += __shfl_xor(sl, 32);
  // lane L holds sum for head L&7; lane h (h<8) holds head h's sum.
  int hh2 = lane >> 3;
  float denom = __shfl(sl, hh2);
  float inv = 1.f / fmaxf(denom, 1e-12f);
  float4 acc = make_float4(0.f, 0.f, 0.f, 0.f);
  for (int p = start; p < end; ++p) {
    int s = src_sorted[p];
    float w = expf(attn[(size_t)p * 8 + hh2] - M) * inv;
    float4 v4 = ((const float4*)(V + (size_t)s * 256))[lane];
    acc.x += v4.x * w;
    acc.y += v4.y * w;
    acc.z += v4.z * w;
    acc.w += v4.w * w;
  }
  ((float4*)(agg + (size_t)node * 256))[lane] = acc;
}

// ---------------------------------------------------------------------------
// h = LayerNorm(h + upd) * gamma + beta (in-place); one wave per row
// ---------------------------------------------------------------------------
__global__ __launch_bounds__(256) void add_ln_k(
    float* __restrict__ h, const float* __restrict__ upd,
    const float* __restrict__ g, const float* __restrict__ b, int n) {
  int row = (blockIdx.x * blockDim.x + threadIdx.x) >> 6;
  if (row >= n) return;
  int lane = threadIdx.x & 63;
  float4 hv = ((const float4*)(h + (size_t)row * 256))[lane];
  float4 uv = ((const float4*)(upd + (size_t)row * 256))[lane];
  float4 s = make_float4(hv.x + uv.x, hv.y + uv.y, hv.z + uv.z, hv.w + uv.w);
  float sum = s.x + s.y + s.z + s.w;
  float sq = s.x * s.x + s.y * s.y + s.z * s.z + s.w * s.w;
  for (int d = 1; d < 64; d <<= 1) {
    sum += __shfl_xor(sum, d);
    sq += __shfl_xor(sq, d);
  }
  float mean = sum * (1.f / 256.f);
  float var = sq * (1.f / 256.f) - mean * mean;
  float r = rsqrtf(var + 1e-5f);
  float4 g4 = ((const float4*)g)[lane];
  float4 b4 = ((const float4*)b)[lane];
  float4 o;
  o.x = (s.x - mean) * r * g4.x + b4.x;
  o.y = (s.y - mean) * r * g4.y + b4.y;
  o.z = (s.z - mean) * r * g4.z + b4.z;
  o.w = (s.w - mean) * r * g4.w + b4.w;
  ((float4*)(h + (size_t)row * 256))[lane] = o;
}

// ---------------------------------------------------------------------------
// out[n] = t[n,:128] @ W_h2 + b_h2 — one wave per row; fp32 out
// ---------------------------------------------------------------------------
__global__ __launch_bounds__(256) void head2_k(
    const float* __restrict__ t, const float* __restrict__ W2,
    const float* __restrict__ b2, float* __restrict__ out, int n) {
  int row = (blockIdx.x * blockDim.x + threadIdx.x) >> 6;
  if (row >= n) return;
  int lane = threadIdx.x & 63;
  float acc = t[(size_t)row * 128 + lane] * W2[lane] +
              t[(size_t)row * 128 + 64 + lane] * W2[64 + lane];
  for (int d = 1; d < 64; d <<= 1) acc += __shfl_xor(acc, d);
  if (lane == 0) out[row] = acc + b2[0];
}

// ---------------------------------------------------------------------------
extern "C" void kernel_launch(void* const* d_in, const int* in_sizes, int n_in,
                              void* d_out, int out_size, void* d_ws,
                              size_t ws_size, hipStream_t stream) {
  const float* x = (const float*)d_in[0];
  const float* edge_attr = (const float*)d_in[1];
  const float* W_in = (const float*)d_in[2];
  const float* b_in = (const float*)d_in[3];
  const float* Wq = (const float*)d_in[4];
  const float* Wk = (const float*)d_in[5];
  const float* Wv = (const float*)d_in[6];
  const float* We = (const float*)d_in[7];
  const float* Wo = (const float*)d_in[8];
  const float* bo = (const float*)d_in[9];
  const float* Wm = (const float*)d_in[10];
  const float* bm = (const float*)d_in[11];
  const float* gamma = (const float*)d_in[12];
  const float* beta = (const float*)d_in[13];
  const float* W_h1 = (const float*)d_in[14];
  const float* b_h1 = (const float*)d_in[15];
  const float* W_h2 = (const float*)d_in[16];
  const float* b_h2 = (const float*)d_in[17];
  const u32* eidx_w = (const u32*)d_in[18];

  // ws budget: proven-safe <= 238 MB (283 MB faulted in R1).
  // h/Qb/Kb/Vb 204.8 + attn 25.6 + src_sorted 3.2 + eorig 3.2 + rowptr/dcnt
  // 0.4 = 237.2 MB. srcI/dstI (6.4 MB) transiently alias the start of Vb.
  float* ws = (float*)d_ws;
  const size_t NH_ = (size_t)N_NODES * HDIM;
  float* h = ws;                                   // N*256, persists
  float* Qb = h + NH_;                             // N*256 (Q -> agg)
  float* Kb = Qb + NH_;                            // N*256 (K -> Wo-out)
  float* Vb = Kb + NH_;                            // N*256 (V -> upd)
  float* attn = Vb + NH_;                          // E*8
  float* part = attn + (size_t)E_EDGES * NHEADS;   // 1024
  float* gmax = part + 1024;                       // 1
  int* idxflag = (int*)(gmax + 1);                 // 1
  int* src_sorted = idxflag + 1;                   // E
  int* eorig = src_sorted + E_EDGES;               // E
  int* rowptr = eorig + E_EDGES;                   // N+1
  int* dcnt = rowptr + N_NODES + 1;                // N
  // transient (dead before any GEMM writes Vb):
  int* srcI = (int*)Vb;                            // E
  int* dstI = srcI + E_EDGES;                      // E

  detect_idx_k<<<1, 256, 0, stream>>>(eidx_w, idxflag);
  convert_idx_k<<<(E_EDGES + 255) / 256, 256, 0, stream>>>(
      eidx_w, idxflag, srcI, dstI, E_EDGES);

  // CSR build (once per call; reused by all 3 layers)
  hipMemsetAsync(dcnt, 0, (size_t)N_NODES * sizeof(int), stream);
  hist_k<<<(E_EDGES + 255) / 256, 256, 0, stream>>>(dstI, dcnt, E_EDGES);
  scan_k<<<1, 256, 0, stream>>>(dcnt, rowptr, N_NODES);
  hipMemsetAsync(dcnt, 0, (size_t)N_NODES * sizeof(int), stream);
  fill_k<<<(E_EDGES + 255) / 256, 256, 0, stream>>>(
      srcI, dstI, rowptr, dcnt, src_sorted, eorig, E_EDGES);

  input_proj_k<<<(N_NODES + 31) / 32, 256, 0, stream>>>(x, W_in, b_in, h,
                                                        N_NODES);
  dim3 g256(HDIM / 64, (N_NODES + 63) / 64);
  const int nodewave_grid = (N_NODES * 64 + 255) / 256;

  for (int l = 0; l < NLAYERS; ++l) {
    const float* Wq_l = Wq + (size_t)l * HDIM * HDIM;
    const float* Wk_l = Wk + (size_t)l * HDIM * HDIM;
    const float* Wv_l = Wv + (size_t)l * HDIM * HDIM;
    const float* We_l = We + (size_t)l * EDGED * NHEADS;
    const float* Wo_l = Wo + (size_t)l * HDIM * HDIM;
    const float* bo_l = bo + (size_t)l * HDIM;
    const float* Wm_l = Wm + (size_t)l * 2 * HDIM * HDIM;
    const float* bm_l = bm + (size_t)l * HDIM;

    gemm_k<false, false><<<g256, 256, 0, stream>>>(
        h, nullptr, Wq_l, nullptr, Qb, N_NODES, HDIM, HDIM, HDIM);
    gemm_k<false, false><<<g256, 256, 0, stream>>>(
        h, nullptr, Wk_l, nullptr, Kb, N_NODES, HDIM, HDIM, HDIM);
    gemm_k<false, false><<<g256, 256, 0, stream>>>(
        h, nullptr, Wv_l, nullptr, Vb, N_NODES, HDIM, HDIM, HDIM);
    node_attn_k<<<nodewave_grid, 256, 0, stream>>>(
        Qb, Kb, edge_attr, We_l, rowptr, src_sorted, eorig, attn, N_NODES);
    rmax1_k<<<1024, 256, 0, stream>>>(attn, E_EDGES * NHEADS, part);
    rmax2_k<<<1, 256, 0, stream>>>(part, 1024, gmax);
    // agg -> Qb (Q dead after node_attn); no memset needed (full overwrite)
    node_agg_k<<<nodewave_grid, 256, 0, stream>>>(
        Vb, attn, gmax, rowptr, src_sorted, Qb, N_NODES);
    // tmp = agg @ Wo + bo -> Kb (K dead)
    gemm_k<false, false><<<g256, 256, 0, stream>>>(
        Qb, nullptr, Wo_l, bo_l, Kb, N_NODES, HDIM, HDIM, HDIM);
    // upd = relu([h | tmp] @ Wm + bm) -> Vb (V dead)
    gemm_k<true, true><<<g256, 256, 0, stream>>>(
        h, Kb, Wm_l, bm_l, Vb, N_NODES, HDIM, 2 * HDIM, HDIM);
    add_ln_k<<<nodewave_grid, 256, 0, stream>>>(h, Vb, gamma + (size_t)l * HDIM,
                                                beta + (size_t)l * HDIM,
                                                N_NODES);
  }
  dim3 gh(128 / 64, (N_NODES + 63) / 64);
  gemm_k<false, true><<<gh, 256, 0, stream>>>(h, nullptr, W_h1, b_h1, Qb,
                                              N_NODES, HDIM, HDIM, 128);
  head2_k<<<nodewave_grid, 256, 0, stream>>>(Qb, W_h2, b_h2, (float*)d_out,
                                             N_NODES);
}

// Round 6
// 1788.050 us; speedup vs baseline: 6.0734x; 1.8249x over previous
//
#include <hip/hip_runtime.h>
#include <math.h>

#define N_NODES 50000
#define E_EDGES 800000
#define HDIM 256
#define NHEADS 8
#define HEADD 32
#define EDGED 3
#define NLAYERS 3

typedef unsigned int u32;
typedef unsigned short ushort_t;
typedef __attribute__((ext_vector_type(8))) short short8;
typedef __attribute__((ext_vector_type(8))) unsigned short ushort8v;
typedef __attribute__((ext_vector_type(4))) float float4v;

__device__ __forceinline__ float bf2f(ushort_t u) {
  union { u32 i; float f; } v;
  v.i = ((u32)u) << 16;
  return v.f;
}
// fp32 -> bf16 RNE
__device__ __forceinline__ ushort_t f2bf(float f) {
  u32 u = __float_as_uint(f);
  u = (u + 0x7FFF + ((u >> 16) & 1)) >> 16;
  return (ushort_t)u;
}

// ---------------------------------------------------------------------------
// edge_index layout detection (int64 vs int32 staging)
// ---------------------------------------------------------------------------
__global__ __launch_bounds__(256) void detect_idx_k(const u32* __restrict__ w,
                                                    int* __restrict__ flag) {
  __shared__ u32 sm[256];
  u32 mx = 0;
  for (int k = threadIdx.x; k < 4096; k += 256) mx = max(mx, w[2 * k + 1]);
  sm[threadIdx.x] = mx;
  __syncthreads();
  for (int s = 128; s > 0; s >>= 1) {
    if (threadIdx.x < s)
      sm[threadIdx.x] = max(sm[threadIdx.x], sm[threadIdx.x + s]);
    __syncthreads();
  }
  if (threadIdx.x == 0) flag[0] = (sm[0] == 0) ? 1 : 0;
}

__global__ __launch_bounds__(256) void convert_idx_k(
    const u32* __restrict__ w, const int* __restrict__ flag,
    int* __restrict__ src32, int* __restrict__ dst32, int E_) {
  int e = blockIdx.x * blockDim.x + threadIdx.x;
  if (e >= E_) return;
  if (flag[0]) {
    src32[e] = (int)w[2 * e];
    dst32[e] = (int)w[2 * (E_ + e)];
  } else {
    src32[e] = (int)w[e];
    dst32[e] = (int)w[E_ + e];
  }
}

// ---------------------------------------------------------------------------
// CSR build: histogram, 3-phase scan, scatter
// ---------------------------------------------------------------------------
__global__ __launch_bounds__(256) void hist_k(const int* __restrict__ dst,
                                              int* __restrict__ dcnt, int E_) {
  int e = blockIdx.x * blockDim.x + threadIdx.x;
  if (e >= E_) return;
  atomicAdd(&dcnt[dst[e]], 1);
}

__global__ __launch_bounds__(256) void scan1_k(const int* __restrict__ deg,
                                               int* __restrict__ scanned,
                                               int* __restrict__ bsum, int n) {
  __shared__ int tmp[256];
  int tid = threadIdx.x;
  int i = blockIdx.x * 256 + tid;
  tmp[tid] = (i < n) ? deg[i] : 0;
  __syncthreads();
  for (int off = 1; off < 256; off <<= 1) {
    int t = (tid >= off) ? tmp[tid - off] : 0;
    __syncthreads();
    tmp[tid] += t;
    __syncthreads();
  }
  if (i < n) scanned[i] = tmp[tid];
  if (tid == 255) bsum[blockIdx.x] = tmp[255];
}

__global__ __launch_bounds__(256) void scan2_k(int* __restrict__ bsum, int nb) {
  __shared__ int tmp[256];
  int tid = threadIdx.x;
  tmp[tid] = (tid < nb) ? bsum[tid] : 0;
  __syncthreads();
  for (int off = 1; off < 256; off <<= 1) {
    int t = (tid >= off) ? tmp[tid - off] : 0;
    __syncthreads();
    tmp[tid] += t;
    __syncthreads();
  }
  if (tid < nb) bsum[tid] = tmp[tid];
}

__global__ __launch_bounds__(256) void scan3_k(const int* __restrict__ scanned,
                                               const int* __restrict__ bsum,
                                               int* __restrict__ rowptr, int n) {
  int i = blockIdx.x * 256 + threadIdx.x;
  if (i < n)
    rowptr[i + 1] = scanned[i] + (blockIdx.x > 0 ? bsum[blockIdx.x - 1] : 0);
  if (i == 0) rowptr[0] = 0;
}

__global__ __launch_bounds__(256) void fill_k(
    const int* __restrict__ srcI, const int* __restrict__ dstI,
    const int* __restrict__ rowptr, int* __restrict__ cursor,
    int* __restrict__ src_sorted, int* __restrict__ eorig, int E_) {
  int e = blockIdx.x * blockDim.x + threadIdx.x;
  if (e >= E_) return;
  int d = dstI[e];
  int p = rowptr[d] + atomicAdd(&cursor[d], 1);
  src_sorted[p] = srcI[e];
  eorig[p] = e;
}

// ---------------------------------------------------------------------------
// Weight transpose+convert: W (K x N fp32) -> WT (N x K bf16), tile 16k x 64n
// ---------------------------------------------------------------------------
__global__ __launch_bounds__(256) void wtrans_k(const float* __restrict__ W,
                                                ushort_t* __restrict__ WT,
                                                int K, int N) {
  __shared__ float t[64][17];
  int k0 = blockIdx.x * 16, n0 = blockIdx.y * 64;
  int tid = threadIdx.x;
  int r = tid >> 6, c = tid & 63;
#pragma unroll
  for (int i = 0; i < 4; ++i)
    t[c][r + 4 * i] = W[(size_t)(k0 + r + 4 * i) * N + n0 + c];
  __syncthreads();
  int n = tid >> 2, j4 = (tid & 3) * 4;
  ushort4 o;
  o.x = f2bf(t[n][j4 + 0]);
  o.y = f2bf(t[n][j4 + 1]);
  o.z = f2bf(t[n][j4 + 2]);
  o.w = f2bf(t[n][j4 + 3]);
  *(ushort4*)&WT[(size_t)(n0 + n) * K + k0 + j4] = o;
}

// ---------------------------------------------------------------------------
// Input projection: h = relu(x @ W_in + b_in); writes fp32 h AND bf16 hbf
// ---------------------------------------------------------------------------
__global__ __launch_bounds__(256) void input_proj_k(
    const float* __restrict__ x, const float* __restrict__ W,
    const float* __restrict__ b, float* __restrict__ h,
    ushort_t* __restrict__ hbf, int n) {
  __shared__ float ws[10 * 256];
  __shared__ float bs[256];
  int tid = threadIdx.x;
  for (int i = tid; i < 2560; i += 256) ws[i] = W[i];
  bs[tid] = b[tid];
  __syncthreads();
  int row0 = blockIdx.x * 32;
  for (int rr = 0; rr < 32; ++rr) {
    int row = row0 + rr;
    if (row >= n) break;
    float acc = bs[tid];
#pragma unroll
    for (int i = 0; i < 10; ++i) acc += x[row * 10 + i] * ws[i * 256 + tid];
    acc = fmaxf(acc, 0.f);
    h[(size_t)row * 256 + tid] = acc;
    hbf[(size_t)row * 256 + tid] = f2bf(acc);
  }
}

// ---------------------------------------------------------------------------
// bf16 MFMA GEMM: C = act(A @ B + bias)
// A1 (M x K1 bf16, row-major); if CONCAT logical A = [A1|A2], Ktot = 2*K1.
// BT (Ncol x Ktot bf16, n-major k-contig). bias fp32 or null.
// Block 256 = 4 waves; tile 128(M) x 64(N); BK=32; wave: 32 rows x 64 cols,
// 2x4 fragments of 16x16, mfma_f32_16x16x32_bf16.
// ---------------------------------------------------------------------------
template <bool CONCAT, bool RELU, bool OUTBF>
__global__ __launch_bounds__(256) void gemm_mfma_k(
    const ushort_t* __restrict__ A1, const ushort_t* __restrict__ A2,
    const ushort_t* __restrict__ BT, const float* __restrict__ bias,
    void* __restrict__ Cout, int M, int K1, int Ktot, int Ncol) {
  __shared__ __align__(16) ushort_t Als[128 * 32];
  __shared__ __align__(16) ushort_t Bls[64 * 32];
  int tid = threadIdx.x;
  int lane = tid & 63, w = tid >> 6;
  int quad = lane >> 4, m = lane & 15;
  int row0 = blockIdx.y * 128, col0 = blockIdx.x * 64;
  float4v acc[2][4];
#pragma unroll
  for (int t = 0; t < 2; ++t)
#pragma unroll
    for (int j = 0; j < 4; ++j) acc[t][j] = (float4v){0.f, 0.f, 0.f, 0.f};

  int arow = tid >> 1, ahalf = (tid & 1) * 16;  // A: 16 bf16 per thread
  int bn = tid >> 2, bq = (tid & 3) * 8;        // B: 8 bf16 per thread

  for (int k0 = 0; k0 < Ktot; k0 += 32) {
    const ushort_t* Ap = A1;
    int kk = k0;
    if (CONCAT && k0 >= K1) { Ap = A2; kk = k0 - K1; }
    int r = row0 + arow;
    if (r < M) {
      const ushort_t* s = Ap + (size_t)r * K1 + kk + ahalf;
      *(ushort8v*)&Als[arow * 32 + ahalf] = *(const ushort8v*)s;
      *(ushort8v*)&Als[arow * 32 + ahalf + 8] = *(const ushort8v*)(s + 8);
    } else {
#pragma unroll
      for (int i = 0; i < 16; ++i) Als[arow * 32 + ahalf + i] = 0;
    }
    *(ushort8v*)&Bls[bn * 32 + bq] =
        *(const ushort8v*)(BT + (size_t)(col0 + bn) * Ktot + k0 + bq);
    __syncthreads();
    short8 a0 = *(const short8*)&Als[(w * 32 + m) * 32 + quad * 8];
    short8 a1 = *(const short8*)&Als[(w * 32 + 16 + m) * 32 + quad * 8];
#pragma unroll
    for (int j = 0; j < 4; ++j) {
      short8 bj = *(const short8*)&Bls[(16 * j + m) * 32 + quad * 8];
      acc[0][j] = __builtin_amdgcn_mfma_f32_16x16x32_bf16(a0, bj, acc[0][j], 0, 0, 0);
      acc[1][j] = __builtin_amdgcn_mfma_f32_16x16x32_bf16(a1, bj, acc[1][j], 0, 0, 0);
    }
    __syncthreads();
  }

#pragma unroll
  for (int t = 0; t < 2; ++t) {
#pragma unroll
    for (int j = 0; j < 4; ++j) {
      int col = col0 + 16 * j + m;
      float bv = bias ? bias[col] : 0.f;
#pragma unroll
      for (int rr = 0; rr < 4; ++rr) {
        int row = row0 + w * 32 + 16 * t + quad * 4 + rr;
        if (row >= M) continue;
        float v = acc[t][j][rr] + bv;
        if (RELU) v = fmaxf(v, 0.f);
        if (OUTBF)
          ((ushort_t*)Cout)[(size_t)row * Ncol + col] = f2bf(v);
        else
          ((float*)Cout)[(size_t)row * Ncol + col] = v;
      }
    }
  }
}

// ---------------------------------------------------------------------------
// Per-node attention logits over CSR segment (bf16 Q,K): one wave per node.
// ---------------------------------------------------------------------------
__global__ __launch_bounds__(256) void node_attn_k(
    const ushort_t* __restrict__ Q, const ushort_t* __restrict__ K,
    const float* __restrict__ ea, const float* __restrict__ We_l,
    const int* __restrict__ rowptr, const int* __restrict__ src_sorted,
    const int* __restrict__ eorig, float* __restrict__ attn, int n) {
  int node = (blockIdx.x * blockDim.x + threadIdx.x) >> 6;
  if (node >= n) return;
  int lane = threadIdx.x & 63;
  ushort4 qu = ((const ushort4*)(Q + (size_t)node * 256))[lane];
  float qx = bf2f(qu.x), qy = bf2f(qu.y), qz = bf2f(qu.z), qw = bf2f(qu.w);
  int start = rowptr[node], end = rowptr[node + 1];
  int hh = lane >> 3;
  float w0 = We_l[0 * 8 + hh], w1 = We_l[1 * 8 + hh], w2 = We_l[2 * 8 + hh];
  for (int p = start; p < end; ++p) {
    int s = src_sorted[p];
    ushort4 ku = ((const ushort4*)(K + (size_t)s * 256))[lane];
    float d = qx * bf2f(ku.x) + qy * bf2f(ku.y) + qz * bf2f(ku.z) +
              qw * bf2f(ku.w);
    d += __shfl_xor(d, 1);
    d += __shfl_xor(d, 2);
    d += __shfl_xor(d, 4);
    if ((lane & 7) == 0) {
      int e = eorig[p];
      float bias = ea[(size_t)e * 3 + 0] * w0 + ea[(size_t)e * 3 + 1] * w1 +
                   ea[(size_t)e * 3 + 2] * w2;
      float a = d * 0.17677669529663687f + bias;  // 1/sqrt(32)
      a = (a > 0.f) ? a : 0.2f * a;               // leaky_relu 0.2
      attn[(size_t)p * 8 + hh] = a;
    }
  }
}

// ---------------------------------------------------------------------------
// Global max, two-stage deterministic
// ---------------------------------------------------------------------------
__global__ __launch_bounds__(256) void rmax1_k(const float* __restrict__ a,
                                               int n, float* __restrict__ part) {
  float m = -INFINITY;
  for (int i = blockIdx.x * blockDim.x + threadIdx.x; i < n;
       i += gridDim.x * blockDim.x)
    m = fmaxf(m, a[i]);
  for (int d = 1; d < 64; d <<= 1) m = fmaxf(m, __shfl_xor(m, d));
  __shared__ float sm[4];
  if ((threadIdx.x & 63) == 0) sm[threadIdx.x >> 6] = m;
  __syncthreads();
  if (threadIdx.x == 0)
    part[blockIdx.x] = fmaxf(fmaxf(sm[0], sm[1]), fmaxf(sm[2], sm[3]));
}

__global__ __launch_bounds__(256) void rmax2_k(const float* __restrict__ part,
                                               int nb, float* __restrict__ gmax) {
  float m = -INFINITY;
  for (int i = threadIdx.x; i < nb; i += 256) m = fmaxf(m, part[i]);
  for (int d = 1; d < 64; d <<= 1) m = fmaxf(m, __shfl_xor(m, d));
  __shared__ float sm[4];
  if ((threadIdx.x & 63) == 0) sm[threadIdx.x >> 6] = m;
  __syncthreads();
  if (threadIdx.x == 0)
    gmax[0] = fmaxf(fmaxf(sm[0], sm[1]), fmaxf(sm[2], sm[3]));
}

// ---------------------------------------------------------------------------
// Per-node softmax + weighted-V aggregation (bf16 V in, bf16 agg out)
// ---------------------------------------------------------------------------
__global__ __launch_bounds__(256) void node_agg_k(
    const ushort_t* __restrict__ V, const float* __restrict__ attn,
    const float* __restrict__ gmax, const int* __restrict__ rowptr,
    const int* __restrict__ src_sorted, ushort_t* __restrict__ agg, int n) {
  int node = (blockIdx.x * blockDim.x + threadIdx.x) >> 6;
  if (node >= n) return;
  int lane = threadIdx.x & 63;
  int start = rowptr[node], end = rowptr[node + 1];
  float M = gmax[0];
  int g = lane >> 3, hh = lane & 7;
  float sl = 0.f;
  for (int p = start + g; p < end; p += 8)
    sl += expf(attn[(size_t)p * 8 + hh] - M);
  sl += __shfl_xor(sl, 8);
  sl += __shfl_xor(sl, 16);
  sl += __shfl_xor(sl, 32);
  int hh2 = lane >> 3;
  float denom = __shfl(sl, hh2);
  float inv = 1.f / fmaxf(denom, 1e-12f);
  float4 acc = make_float4(0.f, 0.f, 0.f, 0.f);
  for (int p = start; p < end; ++p) {
    int s = src_sorted[p];
    float w = expf(attn[(size_t)p * 8 + hh2] - M) * inv;
    ushort4 vu = ((const ushort4*)(V + (size_t)s * 256))[lane];
    acc.x += bf2f(vu.x) * w;
    acc.y += bf2f(vu.y) * w;
    acc.z += bf2f(vu.z) * w;
    acc.w += bf2f(vu.w) * w;
  }
  ushort4 o;
  o.x = f2bf(acc.x);
  o.y = f2bf(acc.y);
  o.z = f2bf(acc.z);
  o.w = f2bf(acc.w);
  ((ushort4*)(agg + (size_t)node * 256))[lane] = o;
}

// ---------------------------------------------------------------------------
// h = LayerNorm(h + upd)*gamma+beta (in-place); also writes bf16 hbf
// ---------------------------------------------------------------------------
__global__ __launch_bounds__(256) void add_ln_k(
    float* __restrict__ h, const float* __restrict__ upd,
    const float* __restrict__ g, const float* __restrict__ b,
    ushort_t* __restrict__ hbf, int n) {
  int row = (blockIdx.x * blockDim.x + threadIdx.x) >> 6;
  if (row >= n) return;
  int lane = threadIdx.x & 63;
  float4 hv = ((const float4*)(h + (size_t)row * 256))[lane];
  float4 uv = ((const float4*)(upd + (size_t)row * 256))[lane];
  float4 s = make_float4(hv.x + uv.x, hv.y + uv.y, hv.z + uv.z, hv.w + uv.w);
  float sum = s.x + s.y + s.z + s.w;
  float sq = s.x * s.x + s.y * s.y + s.z * s.z + s.w * s.w;
  for (int d = 1; d < 64; d <<= 1) {
    sum += __shfl_xor(sum, d);
    sq += __shfl_xor(sq, d);
  }
  float mean = sum * (1.f / 256.f);
  float var = sq * (1.f / 256.f) - mean * mean;
  float r = rsqrtf(var + 1e-5f);
  float4 g4 = ((const float4*)g)[lane];
  float4 b4 = ((const float4*)b)[lane];
  float4 o;
  o.x = (s.x - mean) * r * g4.x + b4.x;
  o.y = (s.y - mean) * r * g4.y + b4.y;
  o.z = (s.z - mean) * r * g4.z + b4.z;
  o.w = (s.w - mean) * r * g4.w + b4.w;
  ((float4*)(h + (size_t)row * 256))[lane] = o;
  ushort4 ob;
  ob.x = f2bf(o.x);
  ob.y = f2bf(o.y);
  ob.z = f2bf(o.z);
  ob.w = f2bf(o.w);
  ((ushort4*)(hbf + (size_t)row * 256))[lane] = ob;
}

// ---------------------------------------------------------------------------
// out[n] = t[n,:128] @ W_h2 + b_h2 — one wave per row; fp32 out
// ---------------------------------------------------------------------------
__global__ __launch_bounds__(256) void head2_k(
    const float* __restrict__ t, const float* __restrict__ W2,
    const float* __restrict__ b2, float* __restrict__ out, int n) {
  int row = (blockIdx.x * blockDim.x + threadIdx.x) >> 6;
  if (row >= n) return;
  int lane = threadIdx.x & 63;
  float acc = t[(size_t)row * 128 + lane] * W2[lane] +
              t[(size_t)row * 128 + 64 + lane] * W2[64 + lane];
  for (int d = 1; d < 64; d <<= 1) acc += __shfl_xor(acc, d);
  if (lane == 0) out[row] = acc + b2[0];
}

// ---------------------------------------------------------------------------
extern "C" void kernel_launch(void* const* d_in, const int* in_sizes, int n_in,
                              void* d_out, int out_size, void* d_ws,
                              size_t ws_size, hipStream_t stream) {
  const float* x = (const float*)d_in[0];
  const float* edge_attr = (const float*)d_in[1];
  const float* W_in = (const float*)d_in[2];
  const float* b_in = (const float*)d_in[3];
  const float* Wq = (const float*)d_in[4];
  const float* Wk = (const float*)d_in[5];
  const float* Wv = (const float*)d_in[6];
  const float* We = (const float*)d_in[7];
  const float* Wo = (const float*)d_in[8];
  const float* bo = (const float*)d_in[9];
  const float* Wm = (const float*)d_in[10];
  const float* bm = (const float*)d_in[11];
  const float* gamma = (const float*)d_in[12];
  const float* beta = (const float*)d_in[13];
  const float* W_h1 = (const float*)d_in[14];
  const float* b_h1 = (const float*)d_in[15];
  const float* W_h2 = (const float*)d_in[16];
  const float* b_h2 = (const float*)d_in[17];
  const u32* eidx_w = (const u32*)d_in[18];

  // ws layout, ~189 MB total (proven-safe budget <= 238 MB):
  // h f32 | hbf bf16 | Kbf | Qbf | Vbf bf16 | attn f32 | misc | CSR | WT
  // Ub (f32 upd, 51.2MB) overlays [Qbf,Vbf]; t (f32 head, 25.6MB) overlays Kbf
  float* ws = (float*)d_ws;
  const size_t NH_ = (size_t)N_NODES * HDIM;
  float* h = ws;
  ushort_t* hbf = (ushort_t*)(h + NH_);
  ushort_t* Kbf = hbf + NH_;
  ushort_t* Qbf = Kbf + NH_;
  ushort_t* Vbf = Qbf + NH_;
  float* Ub = (float*)Qbf;  // overlays Qbf+Vbf (contiguous)
  float* tH = (float*)Kbf;  // head intermediate (N x 128 f32)
  float* attn = (float*)(Vbf + NH_);
  float* part = attn + (size_t)E_EDGES * NHEADS;  // 1024
  float* gmax = part + 1024;
  int* idxflag = (int*)(gmax + 1);
  int* src_sorted = idxflag + 1;            // E
  int* eorig = src_sorted + E_EDGES;        // E
  int* rowptr = eorig + E_EDGES;            // N+1
  int* dcnt = rowptr + N_NODES + 1;         // N
  int* scanned = dcnt + N_NODES;            // N
  int* bsum = scanned + N_NODES;            // 256
  ushort_t* WT = (ushort_t*)(bsum + 256);
  // per-layer transposed weights
  const size_t W64K = (size_t)HDIM * HDIM;      // 65536
  const size_t W128K = (size_t)2 * HDIM * HDIM; // 131072
  ushort_t* WqT = WT;                 // 3 * 64K
  ushort_t* WkT = WqT + 3 * W64K;
  ushort_t* WvT = WkT + 3 * W64K;
  ushort_t* WoT = WvT + 3 * W64K;
  ushort_t* WmT = WoT + 3 * W64K;     // 3 * 128K
  ushort_t* Wh1T = WmT + 3 * W128K;   // 32768
  // transient (consumed before any gemm writes Kbf region):
  int* srcI = (int*)Kbf;
  int* dstI = srcI + E_EDGES;

  detect_idx_k<<<1, 256, 0, stream>>>(eidx_w, idxflag);
  convert_idx_k<<<(E_EDGES + 255) / 256, 256, 0, stream>>>(
      eidx_w, idxflag, srcI, dstI, E_EDGES);

  // CSR build
  hipMemsetAsync(dcnt, 0, (size_t)N_NODES * sizeof(int), stream);
  hist_k<<<(E_EDGES + 255) / 256, 256, 0, stream>>>(dstI, dcnt, E_EDGES);
  const int nsb = (N_NODES + 255) / 256;  // 196
  scan1_k<<<nsb, 256, 0, stream>>>(dcnt, scanned, bsum, N_NODES);
  scan2_k<<<1, 256, 0, stream>>>(bsum, nsb);
  scan3_k<<<nsb, 256, 0, stream>>>(scanned, bsum, rowptr, N_NODES);
  hipMemsetAsync(dcnt, 0, (size_t)N_NODES * sizeof(int), stream);
  fill_k<<<(E_EDGES + 255) / 256, 256, 0, stream>>>(
      srcI, dstI, rowptr, dcnt, src_sorted, eorig, E_EDGES);

  // weight transpose+convert (once per call)
  for (int l = 0; l < NLAYERS; ++l) {
    wtrans_k<<<dim3(16, 4), 256, 0, stream>>>(Wq + l * W64K, WqT + l * W64K,
                                              HDIM, HDIM);
    wtrans_k<<<dim3(16, 4), 256, 0, stream>>>(Wk + l * W64K, WkT + l * W64K,
                                              HDIM, HDIM);
    wtrans_k<<<dim3(16, 4), 256, 0, stream>>>(Wv + l * W64K, WvT + l * W64K,
                                              HDIM, HDIM);
    wtrans_k<<<dim3(16, 4), 256, 0, stream>>>(Wo + l * W64K, WoT + l * W64K,
                                              HDIM, HDIM);
    wtrans_k<<<dim3(32, 4), 256, 0, stream>>>(Wm + l * W128K, WmT + l * W128K,
                                              2 * HDIM, HDIM);
  }
  wtrans_k<<<dim3(16, 2), 256, 0, stream>>>(W_h1, Wh1T, HDIM, HDIM / 2);

  input_proj_k<<<(N_NODES + 31) / 32, 256, 0, stream>>>(x, W_in, b_in, h, hbf,
                                                        N_NODES);
  dim3 gg(HDIM / 64, (N_NODES + 127) / 128);  // (4, 391)
  const int nodewave_grid = (N_NODES * 64 + 255) / 256;

  for (int l = 0; l < NLAYERS; ++l) {
    const float* We_l = We + (size_t)l * EDGED * NHEADS;
    const float* bo_l = bo + (size_t)l * HDIM;
    const float* bm_l = bm + (size_t)l * HDIM;

    gemm_mfma_k<false, false, true><<<gg, 256, 0, stream>>>(
        hbf, nullptr, WqT + l * W64K, nullptr, Qbf, N_NODES, HDIM, HDIM, HDIM);
    gemm_mfma_k<false, false, true><<<gg, 256, 0, stream>>>(
        hbf, nullptr, WkT + l * W64K, nullptr, Kbf, N_NODES, HDIM, HDIM, HDIM);
    gemm_mfma_k<false, false, true><<<gg, 256, 0, stream>>>(
        hbf, nullptr, WvT + l * W64K, nullptr, Vbf, N_NODES, HDIM, HDIM, HDIM);
    node_attn_k<<<nodewave_grid, 256, 0, stream>>>(
        Qbf, Kbf, edge_attr, We_l, rowptr, src_sorted, eorig, attn, N_NODES);
    rmax1_k<<<1024, 256, 0, stream>>>(attn, E_EDGES * NHEADS, part);
    rmax2_k<<<1, 256, 0, stream>>>(part, 1024, gmax);
    // agg (bf16) -> Qbf (Q dead after node_attn)
    node_agg_k<<<nodewave_grid, 256, 0, stream>>>(
        Vbf, attn, gmax, rowptr, src_sorted, Qbf, N_NODES);
    // tmp = agg @ Wo + bo (bf16) -> Kbf (K dead)
    gemm_mfma_k<false, false, true><<<gg, 256, 0, stream>>>(
        Qbf, nullptr, WoT + l * W64K, bo_l, Kbf, N_NODES, HDIM, HDIM, HDIM);
    // upd = relu([hbf|Kbf] @ Wm + bm) fp32 -> Ub (overlays Qbf+Vbf, both dead)
    gemm_mfma_k<true, true, false><<<gg, 256, 0, stream>>>(
        hbf, Kbf, WmT + l * W128K, bm_l, Ub, N_NODES, HDIM, 2 * HDIM, HDIM);
    add_ln_k<<<nodewave_grid, 256, 0, stream>>>(
        h, Ub, gamma + (size_t)l * HDIM, beta + (size_t)l * HDIM, hbf, N_NODES);
  }
  // head: t = relu(hbf @ W_h1 + b_h1) fp32 -> tH (overlays Kbf, dead)
  dim3 gh((HDIM / 2) / 64, (N_NODES + 127) / 128);  // (2, 391)
  gemm_mfma_k<false, true, false><<<gh, 256, 0, stream>>>(
      hbf, nullptr, Wh1T, b_h1, tH, N_NODES, HDIM, HDIM, HDIM / 2);
  head2_k<<<nodewave_grid, 256, 0, stream>>>(tH, W_h2, b_h2, (float*)d_out,
                                             N_NODES);
}

// Round 7
// 1219.042 us; speedup vs baseline: 8.9083x; 1.4668x over previous
//
#include <hip/hip_runtime.h>
#include <math.h>

#define N_NODES 50000
#define E_EDGES 800000
#define HDIM 256
#define NHEADS 8
#define HEADD 32
#define EDGED 3
#define NLAYERS 3

typedef unsigned int u32;
typedef unsigned short ushort_t;
typedef __attribute__((ext_vector_type(8))) short short8;
typedef __attribute__((ext_vector_type(8))) unsigned short ushort8v;
typedef __attribute__((ext_vector_type(4))) float float4v;

__device__ __forceinline__ float bf2f(ushort_t u) {
  union { u32 i; float f; } v;
  v.i = ((u32)u) << 16;
  return v.f;
}
// fp32 -> bf16 RNE
__device__ __forceinline__ ushort_t f2bf(float f) {
  u32 u = __float_as_uint(f);
  u = (u + 0x7FFF + ((u >> 16) & 1)) >> 16;
  return (ushort_t)u;
}

// ---------------------------------------------------------------------------
// edge_index layout detection (int64 vs int32 staging)
// ---------------------------------------------------------------------------
__global__ __launch_bounds__(256) void detect_idx_k(const u32* __restrict__ w,
                                                    int* __restrict__ flag) {
  __shared__ u32 sm[256];
  u32 mx = 0;
  for (int k = threadIdx.x; k < 4096; k += 256) mx = max(mx, w[2 * k + 1]);
  sm[threadIdx.x] = mx;
  __syncthreads();
  for (int s = 128; s > 0; s >>= 1) {
    if (threadIdx.x < s)
      sm[threadIdx.x] = max(sm[threadIdx.x], sm[threadIdx.x + s]);
    __syncthreads();
  }
  if (threadIdx.x == 0) flag[0] = (sm[0] == 0) ? 1 : 0;
}

__global__ __launch_bounds__(256) void convert_idx_k(
    const u32* __restrict__ w, const int* __restrict__ flag,
    int* __restrict__ src32, int* __restrict__ dst32, int E_) {
  int e = blockIdx.x * blockDim.x + threadIdx.x;
  if (e >= E_) return;
  if (flag[0]) {
    src32[e] = (int)w[2 * e];
    dst32[e] = (int)w[2 * (E_ + e)];
  } else {
    src32[e] = (int)w[e];
    dst32[e] = (int)w[E_ + e];
  }
}

// ---------------------------------------------------------------------------
// CSR build: histogram, 3-phase scan, scatter
// ---------------------------------------------------------------------------
__global__ __launch_bounds__(256) void hist_k(const int* __restrict__ dst,
                                              int* __restrict__ dcnt, int E_) {
  int e = blockIdx.x * blockDim.x + threadIdx.x;
  if (e >= E_) return;
  atomicAdd(&dcnt[dst[e]], 1);
}

__global__ __launch_bounds__(256) void scan1_k(const int* __restrict__ deg,
                                               int* __restrict__ scanned,
                                               int* __restrict__ bsum, int n) {
  __shared__ int tmp[256];
  int tid = threadIdx.x;
  int i = blockIdx.x * 256 + tid;
  tmp[tid] = (i < n) ? deg[i] : 0;
  __syncthreads();
  for (int off = 1; off < 256; off <<= 1) {
    int t = (tid >= off) ? tmp[tid - off] : 0;
    __syncthreads();
    tmp[tid] += t;
    __syncthreads();
  }
  if (i < n) scanned[i] = tmp[tid];
  if (tid == 255) bsum[blockIdx.x] = tmp[255];
}

__global__ __launch_bounds__(256) void scan2_k(int* __restrict__ bsum, int nb) {
  __shared__ int tmp[256];
  int tid = threadIdx.x;
  tmp[tid] = (tid < nb) ? bsum[tid] : 0;
  __syncthreads();
  for (int off = 1; off < 256; off <<= 1) {
    int t = (tid >= off) ? tmp[tid - off] : 0;
    __syncthreads();
    tmp[tid] += t;
    __syncthreads();
  }
  if (tid < nb) bsum[tid] = tmp[tid];
}

__global__ __launch_bounds__(256) void scan3_k(const int* __restrict__ scanned,
                                               const int* __restrict__ bsum,
                                               int* __restrict__ rowptr, int n) {
  int i = blockIdx.x * 256 + threadIdx.x;
  if (i < n)
    rowptr[i + 1] = scanned[i] + (blockIdx.x > 0 ? bsum[blockIdx.x - 1] : 0);
  if (i == 0) rowptr[0] = 0;
}

__global__ __launch_bounds__(256) void fill_k(
    const int* __restrict__ srcI, const int* __restrict__ dstI,
    const int* __restrict__ rowptr, int* __restrict__ cursor,
    int* __restrict__ src_sorted, int* __restrict__ eorig, int E_) {
  int e = blockIdx.x * blockDim.x + threadIdx.x;
  if (e >= E_) return;
  int d = dstI[e];
  int p = rowptr[d] + atomicAdd(&cursor[d], 1);
  src_sorted[p] = srcI[e];
  eorig[p] = e;
}

// ---------------------------------------------------------------------------
// Weight transpose+convert: W (K x N fp32) -> WT (N x K bf16), tile 16k x 64n
// ---------------------------------------------------------------------------
__global__ __launch_bounds__(256) void wtrans_k(const float* __restrict__ W,
                                                ushort_t* __restrict__ WT,
                                                int K, int N) {
  __shared__ float t[64][17];
  int k0 = blockIdx.x * 16, n0 = blockIdx.y * 64;
  int tid = threadIdx.x;
  int r = tid >> 6, c = tid & 63;
#pragma unroll
  for (int i = 0; i < 4; ++i)
    t[c][r + 4 * i] = W[(size_t)(k0 + r + 4 * i) * N + n0 + c];
  __syncthreads();
  int n = tid >> 2, j4 = (tid & 3) * 4;
  ushort4 o;
  o.x = f2bf(t[n][j4 + 0]);
  o.y = f2bf(t[n][j4 + 1]);
  o.z = f2bf(t[n][j4 + 2]);
  o.w = f2bf(t[n][j4 + 3]);
  *(ushort4*)&WT[(size_t)(n0 + n) * K + k0 + j4] = o;
}

// ---------------------------------------------------------------------------
// Input projection: h = relu(x @ W_in + b_in); writes fp32 h AND bf16 hbf
// ---------------------------------------------------------------------------
__global__ __launch_bounds__(256) void input_proj_k(
    const float* __restrict__ x, const float* __restrict__ W,
    const float* __restrict__ b, float* __restrict__ h,
    ushort_t* __restrict__ hbf, int n) {
  __shared__ float ws[10 * 256];
  __shared__ float bs[256];
  int tid = threadIdx.x;
  for (int i = tid; i < 2560; i += 256) ws[i] = W[i];
  bs[tid] = b[tid];
  __syncthreads();
  int row0 = blockIdx.x * 32;
  for (int rr = 0; rr < 32; ++rr) {
    int row = row0 + rr;
    if (row >= n) break;
    float acc = bs[tid];
#pragma unroll
    for (int i = 0; i < 10; ++i) acc += x[row * 10 + i] * ws[i * 256 + tid];
    acc = fmaxf(acc, 0.f);
    h[(size_t)row * 256 + tid] = acc;
    hbf[(size_t)row * 256 + tid] = f2bf(acc);
  }
}

// ---------------------------------------------------------------------------
// bf16 MFMA GEMM: C = act(A @ B + bias) — as round 6
// ---------------------------------------------------------------------------
template <bool CONCAT, bool RELU, bool OUTBF>
__global__ __launch_bounds__(256) void gemm_mfma_k(
    const ushort_t* __restrict__ A1, const ushort_t* __restrict__ A2,
    const ushort_t* __restrict__ BT, const float* __restrict__ bias,
    void* __restrict__ Cout, int M, int K1, int Ktot, int Ncol) {
  __shared__ __align__(16) ushort_t Als[128 * 32];
  __shared__ __align__(16) ushort_t Bls[64 * 32];
  int tid = threadIdx.x;
  int lane = tid & 63, w = tid >> 6;
  int quad = lane >> 4, m = lane & 15;
  int row0 = blockIdx.y * 128, col0 = blockIdx.x * 64;
  float4v acc[2][4];
#pragma unroll
  for (int t = 0; t < 2; ++t)
#pragma unroll
    for (int j = 0; j < 4; ++j) acc[t][j] = (float4v){0.f, 0.f, 0.f, 0.f};

  int arow = tid >> 1, ahalf = (tid & 1) * 16;
  int bn = tid >> 2, bq = (tid & 3) * 8;

  for (int k0 = 0; k0 < Ktot; k0 += 32) {
    const ushort_t* Ap = A1;
    int kk = k0;
    if (CONCAT && k0 >= K1) { Ap = A2; kk = k0 - K1; }
    int r = row0 + arow;
    if (r < M) {
      const ushort_t* s = Ap + (size_t)r * K1 + kk + ahalf;
      *(ushort8v*)&Als[arow * 32 + ahalf] = *(const ushort8v*)s;
      *(ushort8v*)&Als[arow * 32 + ahalf + 8] = *(const ushort8v*)(s + 8);
    } else {
#pragma unroll
      for (int i = 0; i < 16; ++i) Als[arow * 32 + ahalf + i] = 0;
    }
    *(ushort8v*)&Bls[bn * 32 + bq] =
        *(const ushort8v*)(BT + (size_t)(col0 + bn) * Ktot + k0 + bq);
    __syncthreads();
    short8 a0 = *(const short8*)&Als[(w * 32 + m) * 32 + quad * 8];
    short8 a1 = *(const short8*)&Als[(w * 32 + 16 + m) * 32 + quad * 8];
#pragma unroll
    for (int j = 0; j < 4; ++j) {
      short8 bj = *(const short8*)&Bls[(16 * j + m) * 32 + quad * 8];
      acc[0][j] = __builtin_amdgcn_mfma_f32_16x16x32_bf16(a0, bj, acc[0][j], 0, 0, 0);
      acc[1][j] = __builtin_amdgcn_mfma_f32_16x16x32_bf16(a1, bj, acc[1][j], 0, 0, 0);
    }
    __syncthreads();
  }

#pragma unroll
  for (int t = 0; t < 2; ++t) {
#pragma unroll
    for (int j = 0; j < 4; ++j) {
      int col = col0 + 16 * j + m;
      float bv = bias ? bias[col] : 0.f;
#pragma unroll
      for (int rr = 0; rr < 4; ++rr) {
        int row = row0 + w * 32 + 16 * t + quad * 4 + rr;
        if (row >= M) continue;
        float v = acc[t][j][rr] + bv;
        if (RELU) v = fmaxf(v, 0.f);
        if (OUTBF)
          ((ushort_t*)Cout)[(size_t)row * Ncol + col] = f2bf(v);
        else
          ((float*)Cout)[(size_t)row * Ncol + col] = v;
      }
    }
  }
}

// ---------------------------------------------------------------------------
// FUSED edge phase: per-node online-softmax attention + V aggregation.
// One wave per node; half-wave (32 lanes) per edge slot => 2 edges in flight.
// Each lane covers 8 dims (ushort8 = 16B loads). Head = (lane&31)>>2.
// Per-node max stabilization (mathematically identical to the reference's
// global-max form; the max cancels in the softmax ratio).
// QKV layout: row stride 768 (Q | K | V). agg out bf16 (N x 256).
// ---------------------------------------------------------------------------
__global__ __launch_bounds__(256) void node_fused_k(
    const ushort_t* __restrict__ QKV, const float* __restrict__ ea,
    const float* __restrict__ We_l, const int* __restrict__ rowptr,
    const int* __restrict__ src_sorted, const int* __restrict__ eorig,
    ushort_t* __restrict__ agg, int n) {
  int node = (blockIdx.x * blockDim.x + threadIdx.x) >> 6;
  if (node >= n) return;
  int lane = threadIdx.x & 63;
  int hl = lane & 31;   // lane in half-wave
  int slot = lane >> 5; // which edge of the pair
  ushort8v qu = *((const ushort8v*)(QKV + (size_t)node * 768) + hl);
  float q[8];
#pragma unroll
  for (int i = 0; i < 8; ++i) q[i] = bf2f(qu[i]);
  int start = rowptr[node], end = rowptr[node + 1];
  int hh = hl >> 2;
  float w0 = We_l[0 * 8 + hh], w1 = We_l[1 * 8 + hh], w2 = We_l[2 * 8 + hh];
  float m = -INFINITY, l = 0.f;
  float acc[8];
#pragma unroll
  for (int i = 0; i < 8; ++i) acc[i] = 0.f;

  int iters = (end - start + 1) >> 1;
  for (int it = 0; it < iters; ++it) {
    int p = start + 2 * it + slot;
    if (p < end) {
      int s = src_sorted[p];
      const ushort_t* base = QKV + (size_t)s * 768;
      ushort8v ku = *((const ushort8v*)(base + 256) + hl);
      ushort8v vu = *((const ushort8v*)(base + 512) + hl);
      float d = 0.f;
#pragma unroll
      for (int i = 0; i < 8; ++i) d += q[i] * bf2f(ku[i]);
      d += __shfl_xor(d, 1);
      d += __shfl_xor(d, 2);  // full head dot in each 4-lane group
      int e = eorig[p];
      float bias = ea[(size_t)e * 3 + 0] * w0 + ea[(size_t)e * 3 + 1] * w1 +
                   ea[(size_t)e * 3 + 2] * w2;
      float a = d * 0.17677669529663687f + bias;  // 1/sqrt(32)
      a = (a > 0.f) ? a : 0.2f * a;               // leaky_relu 0.2
      float mn = fmaxf(m, a);
      float sc = __expf(m - mn);  // m=-inf first time -> 0
      float wv = __expf(a - mn);
      l = l * sc + wv;
#pragma unroll
      for (int i = 0; i < 8; ++i) acc[i] = acc[i] * sc + bf2f(vu[i]) * wv;
      m = mn;
    }
  }
  // merge the two half-wave online states
  float m2 = __shfl_xor(m, 32);
  float l2 = __shfl_xor(l, 32);
  float mn = fmaxf(fmaxf(m, m2), -1e30f);  // -1e30 guards degree-0 (NaN-free)
  float s1 = __expf(m - mn), s2 = __expf(m2 - mn);
  l = l * s1 + l2 * s2;
  float inv = 1.f / fmaxf(l, 1e-12f);
  ushort8v o;
#pragma unroll
  for (int i = 0; i < 8; ++i) {
    float v = (acc[i] * s1 + __shfl_xor(acc[i], 32) * s2) * inv;
    o[i] = f2bf(v);
  }
  if (slot == 0)
    *((ushort8v*)(agg + (size_t)node * 256) + hl) = o;
}

// ---------------------------------------------------------------------------
// h = LayerNorm(h + upd)*gamma+beta (in-place); also writes bf16 hbf
// ---------------------------------------------------------------------------
__global__ __launch_bounds__(256) void add_ln_k(
    float* __restrict__ h, const float* __restrict__ upd,
    const float* __restrict__ g, const float* __restrict__ b,
    ushort_t* __restrict__ hbf, int n) {
  int row = (blockIdx.x * blockDim.x + threadIdx.x) >> 6;
  if (row >= n) return;
  int lane = threadIdx.x & 63;
  float4 hv = ((const float4*)(h + (size_t)row * 256))[lane];
  float4 uv = ((const float4*)(upd + (size_t)row * 256))[lane];
  float4 s = make_float4(hv.x + uv.x, hv.y + uv.y, hv.z + uv.z, hv.w + uv.w);
  float sum = s.x + s.y + s.z + s.w;
  float sq = s.x * s.x + s.y * s.y + s.z * s.z + s.w * s.w;
  for (int d = 1; d < 64; d <<= 1) {
    sum += __shfl_xor(sum, d);
    sq += __shfl_xor(sq, d);
  }
  float mean = sum * (1.f / 256.f);
  float var = sq * (1.f / 256.f) - mean * mean;
  float r = rsqrtf(var + 1e-5f);
  float4 g4 = ((const float4*)g)[lane];
  float4 b4 = ((const float4*)b)[lane];
  float4 o;
  o.x = (s.x - mean) * r * g4.x + b4.x;
  o.y = (s.y - mean) * r * g4.y + b4.y;
  o.z = (s.z - mean) * r * g4.z + b4.z;
  o.w = (s.w - mean) * r * g4.w + b4.w;
  ((float4*)(h + (size_t)row * 256))[lane] = o;
  ushort4 ob;
  ob.x = f2bf(o.x);
  ob.y = f2bf(o.y);
  ob.z = f2bf(o.z);
  ob.w = f2bf(o.w);
  ((ushort4*)(hbf + (size_t)row * 256))[lane] = ob;
}

// ---------------------------------------------------------------------------
// out[n] = t[n,:128] @ W_h2 + b_h2 — one wave per row; fp32 out
// ---------------------------------------------------------------------------
__global__ __launch_bounds__(256) void head2_k(
    const float* __restrict__ t, const float* __restrict__ W2,
    const float* __restrict__ b2, float* __restrict__ out, int n) {
  int row = (blockIdx.x * blockDim.x + threadIdx.x) >> 6;
  if (row >= n) return;
  int lane = threadIdx.x & 63;
  float acc = t[(size_t)row * 128 + lane] * W2[lane] +
              t[(size_t)row * 128 + 64 + lane] * W2[64 + lane];
  for (int d = 1; d < 64; d <<= 1) acc += __shfl_xor(acc, d);
  if (lane == 0) out[row] = acc + b2[0];
}

// ---------------------------------------------------------------------------
extern "C" void kernel_launch(void* const* d_in, const int* in_sizes, int n_in,
                              void* d_out, int out_size, void* d_ws,
                              size_t ws_size, hipStream_t stream) {
  const float* x = (const float*)d_in[0];
  const float* edge_attr = (const float*)d_in[1];
  const float* W_in = (const float*)d_in[2];
  const float* b_in = (const float*)d_in[3];
  const float* Wq = (const float*)d_in[4];
  const float* Wk = (const float*)d_in[5];
  const float* Wv = (const float*)d_in[6];
  const float* We = (const float*)d_in[7];
  const float* Wo = (const float*)d_in[8];
  const float* bo = (const float*)d_in[9];
  const float* Wm = (const float*)d_in[10];
  const float* bm = (const float*)d_in[11];
  const float* gamma = (const float*)d_in[12];
  const float* beta = (const float*)d_in[13];
  const float* W_h1 = (const float*)d_in[14];
  const float* b_h1 = (const float*)d_in[15];
  const float* W_h2 = (const float*)d_in[16];
  const float* b_h2 = (const float*)d_in[17];
  const u32* eidx_w = (const u32*)d_in[18];

  // ws layout (~214 MB, proven-safe <= 238 MB):
  // h f32 51.2 | hbf 25.6 | QKVbf 76.8 | aggbf 25.6 | tmpbf 25.6 | CSR ~7 | WT 2.5
  // Ub (f32 upd, 51.2) and tH (f32 head) overlay QKVbf; srcI/dstI overlay QKVbf.
  float* ws = (float*)d_ws;
  const size_t NH_ = (size_t)N_NODES * HDIM;
  float* h = ws;
  ushort_t* hbf = (ushort_t*)(h + NH_);
  ushort_t* QKVbf = hbf + NH_;              // N x 768
  ushort_t* aggbf = QKVbf + (size_t)N_NODES * 768;
  ushort_t* tmpbf = aggbf + NH_;
  float* Ub = (float*)QKVbf;                // N x 256 f32 (overlay)
  float* tH = (float*)QKVbf;                // N x 128 f32 (overlay)
  int* idxflag = (int*)(tmpbf + NH_);
  int* src_sorted = idxflag + 1;            // E
  int* eorig = src_sorted + E_EDGES;        // E
  int* rowptr = eorig + E_EDGES;            // N+1
  int* dcnt = rowptr + N_NODES + 1;         // N
  int* scanned = dcnt + N_NODES;            // N
  int* bsum = scanned + N_NODES;            // 256
  ushort_t* WT = (ushort_t*)(bsum + 256);
  const size_t W64K = (size_t)HDIM * HDIM;
  const size_t W128K = (size_t)2 * HDIM * HDIM;
  ushort_t* WqkvT = WT;                     // 3 layers x (768 x 256)
  ushort_t* WoT = WqkvT + 3 * 3 * W64K;
  ushort_t* WmT = WoT + 3 * W64K;
  ushort_t* Wh1T = WmT + 3 * W128K;
  // transient: consumed by fill_k before any GEMM writes QKVbf
  int* srcI = (int*)QKVbf;
  int* dstI = srcI + E_EDGES;

  detect_idx_k<<<1, 256, 0, stream>>>(eidx_w, idxflag);
  convert_idx_k<<<(E_EDGES + 255) / 256, 256, 0, stream>>>(
      eidx_w, idxflag, srcI, dstI, E_EDGES);

  // CSR build
  hipMemsetAsync(dcnt, 0, (size_t)N_NODES * sizeof(int), stream);
  hist_k<<<(E_EDGES + 255) / 256, 256, 0, stream>>>(dstI, dcnt, E_EDGES);
  const int nsb = (N_NODES + 255) / 256;
  scan1_k<<<nsb, 256, 0, stream>>>(dcnt, scanned, bsum, N_NODES);
  scan2_k<<<1, 256, 0, stream>>>(bsum, nsb);
  scan3_k<<<nsb, 256, 0, stream>>>(scanned, bsum, rowptr, N_NODES);
  hipMemsetAsync(dcnt, 0, (size_t)N_NODES * sizeof(int), stream);
  fill_k<<<(E_EDGES + 255) / 256, 256, 0, stream>>>(
      srcI, dstI, rowptr, dcnt, src_sorted, eorig, E_EDGES);

  // weight transpose+convert; QKV concatenated along N (rows of BT):
  // rows 0-255 = WqT, 256-511 = WkT, 512-767 = WvT, per layer.
  for (int l = 0; l < NLAYERS; ++l) {
    ushort_t* base = WqkvT + (size_t)l * 3 * W64K;
    wtrans_k<<<dim3(16, 4), 256, 0, stream>>>(Wq + l * W64K, base, HDIM, HDIM);
    wtrans_k<<<dim3(16, 4), 256, 0, stream>>>(Wk + l * W64K, base + W64K, HDIM,
                                              HDIM);
    wtrans_k<<<dim3(16, 4), 256, 0, stream>>>(Wv + l * W64K, base + 2 * W64K,
                                              HDIM, HDIM);
    wtrans_k<<<dim3(16, 4), 256, 0, stream>>>(Wo + l * W64K, WoT + l * W64K,
                                              HDIM, HDIM);
    wtrans_k<<<dim3(32, 4), 256, 0, stream>>>(Wm + l * W128K, WmT + l * W128K,
                                              2 * HDIM, HDIM);
  }
  wtrans_k<<<dim3(16, 2), 256, 0, stream>>>(W_h1, Wh1T, HDIM, HDIM / 2);

  input_proj_k<<<(N_NODES + 31) / 32, 256, 0, stream>>>(x, W_in, b_in, h, hbf,
                                                        N_NODES);
  dim3 gqkv(768 / 64, (N_NODES + 127) / 128);   // (12, 391)
  dim3 gg(HDIM / 64, (N_NODES + 127) / 128);    // (4, 391)
  const int nodewave_grid = (N_NODES * 64 + 255) / 256;

  for (int l = 0; l < NLAYERS; ++l) {
    const float* We_l = We + (size_t)l * EDGED * NHEADS;
    const float* bo_l = bo + (size_t)l * HDIM;
    const float* bm_l = bm + (size_t)l * HDIM;

    // QKV = hbf @ [Wq|Wk|Wv]  (N x 768 bf16)
    gemm_mfma_k<false, false, true><<<gqkv, 256, 0, stream>>>(
        hbf, nullptr, WqkvT + (size_t)l * 3 * W64K, nullptr, QKVbf, N_NODES,
        HDIM, HDIM, 768);
    // fused attention + softmax + aggregation (per-node online max)
    node_fused_k<<<nodewave_grid, 256, 0, stream>>>(
        QKVbf, edge_attr, We_l, rowptr, src_sorted, eorig, aggbf, N_NODES);
    // tmp = agg @ Wo + bo (bf16)
    gemm_mfma_k<false, false, true><<<gg, 256, 0, stream>>>(
        aggbf, nullptr, WoT + l * W64K, bo_l, tmpbf, N_NODES, HDIM, HDIM,
        HDIM);
    // upd = relu([hbf|tmpbf] @ Wm + bm) fp32 -> Ub (overlays QKVbf, dead)
    gemm_mfma_k<true, true, false><<<gg, 256, 0, stream>>>(
        hbf, tmpbf, WmT + l * W128K, bm_l, Ub, N_NODES, HDIM, 2 * HDIM, HDIM);
    add_ln_k<<<nodewave_grid, 256, 0, stream>>>(
        h, Ub, gamma + (size_t)l * HDIM, beta + (size_t)l * HDIM, hbf, N_NODES);
  }
  // head: t = relu(hbf @ W_h1 + b_h1) fp32 -> tH (overlays QKVbf)
  dim3 gh((HDIM / 2) / 64, (N_NODES + 127) / 128);
  gemm_mfma_k<false, true, false><<<gh, 256, 0, stream>>>(
      hbf, nullptr, Wh1T, b_h1, tH, N_NODES, HDIM, HDIM, HDIM / 2);
  head2_k<<<nodewave_grid, 256, 0, stream>>>(tH, W_h2, b_h2, (float*)d_out,
                                             N_NODES);
}